// Round 14
// baseline (230.394 us; speedup 1.0000x reference)
//
#include <hip/hip_runtime.h>
#include <cstdint>

#define CONF_THRES 0.25f
#define IOU_THRES  0.45f
#define MAX_DET    300
#define K_TOP      8192
#define NA         102000
#define NCLS       80
#define ROWLEN     85
#define CAP        32640
#define NPLANE     32
#define WIN        512
#define NWIN       (K_TOP / WIN)
#define SSTR       9            // LDS row stride in u64 (pad 8->9: bank spread)

typedef unsigned long long u64;
typedef unsigned int u32;

// ---------------- kernel 1: wave-per-anchor scores -> sortable keys + histogram ----
__global__ __launch_bounds__(256) void score_key_kernel(const float* __restrict__ preds,
        u64* __restrict__ keys, u32* __restrict__ histP) {
#pragma clang fp contract(off)
    int lane = threadIdx.x & 63;
    int i = blockIdx.x * 4 + (threadIdx.x >> 6);     // 4 waves/block, 1 anchor/wave
    if (i >= NA) return;
    const float* p = preds + (size_t)i * ROWLEN;
    float v0 = p[lane];                               // offsets 0..63
    float v1 = (lane < ROWLEN - 64) ? p[64 + lane] : 0.0f; // offsets 64..84
    float obj = __shfl(v0, 4);
    float m = (lane >= 5) ? v0 : 0.0f;                // classes 0..58 (scores >= 0)
    m = fmaxf(m, (lane < 21) ? v1 : 0.0f);            // classes 59..79
    for (int off = 32; off; off >>= 1) m = fmaxf(m, __shfl_xor(m, off));
    if (lane == 0) {
        float score = (obj > CONF_THRES) ? m * obj : 0.0f;
        u32 sb = __float_as_uint(score);              // score >= 0: order-preserving bits
        keys[i] = ((u64)sb << 32) | (u32)(~(u32)i);   // tie-break: smaller index wins
        if (sb != 0u)
            atomicAdd(&histP[((u32)blockIdx.x & (NPLANE - 1u)) * 65536u + (sb >> 16)], 1u);
    }
}

// ---------------- kernel 1b: fold 32 histogram planes -> sumhist ----------------
__global__ __launch_bounds__(256) void reduce_hist_kernel(const u32* __restrict__ histP,
        u32* __restrict__ sumhist) {
    int bin = blockIdx.x * 256 + threadIdx.x;         // grid 256 -> 65536 bins
    u32 s = 0;
#pragma unroll
    for (int r = 0; r < NPLANE; ++r) s += histP[r * 65536 + bin];
    sumhist[bin] = s;
}

// ---------------- kernel 2: find threshold bucket for top-K (parallel scan) --------
__global__ __launch_bounds__(1024) void cutoff_kernel(const u32* __restrict__ hist,
        u32* __restrict__ meta) {
    __shared__ u32 suf[1024];
    __shared__ int cbs;
    __shared__ u32 above_s;
    int t = threadIdx.x;
    u32 s = 0;
    const u32* hb = hist + t * 64;
    for (int b = 0; b < 64; ++b) s += hb[b];
    suf[t] = s;
    if (t == 0) { cbs = -1; above_s = 0; }
    __syncthreads();
    for (int off = 1; off < 1024; off <<= 1) {
        u32 add = (t + off < 1024) ? suf[t + off] : 0u;
        __syncthreads();
        suf[t] += add;
        __syncthreads();
    }
    u32 st = suf[t];
    u32 stn = (t < 1023) ? suf[t + 1] : 0u;
    if (st >= (u32)K_TOP && stn < (u32)K_TOP) {       // at most one thread
        cbs = t;
        above_s = stn;                                 // sum of chunks above cb
    }
    __syncthreads();
    int cb = cbs;
    if (t < 64) {                                      // wave 0 does the fine pass
        u32 thresh = 0;
        if (cb >= 0) {
            u32 above = above_s;
            u32 v = hist[cb * 64 + t];
            for (int off = 1; off < 64; off <<= 1) {
                u32 o = __shfl_down(v, off);
                if (t + off < 64) v += o;
            }
            u64 bal = __ballot(v + above >= (u32)K_TOP);
            int bstar = 63 - __builtin_clzll((unsigned long long)bal);
            thresh = ((u32)(cb * 64 + bstar)) << 16;
        }
        if (t == 0) meta[1] = thresh;                  // meta[0] zeroed by memset
    }
}

// ---------------- kernel 3: compact candidates above threshold ----------------
__global__ __launch_bounds__(256) void compact_kernel(const u64* __restrict__ keys,
        u32* __restrict__ meta, u64* __restrict__ comp) {
    __shared__ u32 woff[4];
    __shared__ u32 bbase;
    int i = blockIdx.x * 256 + threadIdx.x;
    int wid = threadIdx.x >> 6, lane = threadIdx.x & 63;
    u64 key = (i < NA) ? keys[i] : 0ull;
    u32 sb = (u32)(key >> 32);
    u32 th = meta[1];
    bool take = (i < NA) && (sb != 0u) && (sb >= th);
    u64 bal = __ballot(take);
    if (lane == 0) woff[wid] = (u32)__popcll(bal);
    __syncthreads();
    if (threadIdx.x == 0) {
        u32 t0 = woff[0], t1 = woff[1], t2 = woff[2], t3 = woff[3];
        bbase = atomicAdd(&meta[0], t0 + t1 + t2 + t3);
        woff[0] = 0; woff[1] = t0; woff[2] = t0 + t1; woff[3] = t0 + t1 + t2;
    }
    __syncthreads();
    if (take) {
        u32 pos = bbase + woff[wid] + (u32)__popcll(bal & ((1ull << lane) - 1ull));
        if (pos < CAP) comp[pos] = key;
    }
}

// ---------------- kernel 4a: 2-D partial rank-by-counting ----------------
__global__ __launch_bounds__(256) void rank_partial_kernel(const u64* __restrict__ comp,
        const u32* __restrict__ meta, u32* __restrict__ rankArr) {
    __shared__ u64 tile[1024];
    u32 cnt = meta[0];
    int n = (int)(cnt < (u32)CAP ? cnt : (u32)CAP);
    int i0 = blockIdx.x * 256;
    int j0 = blockIdx.y * 1024;
    if (i0 >= n || j0 >= n) return;                  // uniform early exit
    int lim = n - j0; if (lim > 1024) lim = 1024;
    for (int k = threadIdx.x; k < 1024; k += 256)
        tile[k] = (k < lim) ? comp[j0 + k] : 0ull;
    __syncthreads();
    int i = i0 + threadIdx.x;
    if (i < n) {
        u64 key = comp[i];
        u32 r = 0;
#pragma unroll 8
        for (int j = 0; j < 1024; ++j) r += (tile[j] > key) ? 1u : 0u;
        atomicAdd(&rankArr[i], r);
    }
}

// ---------------- kernel 4b: scatter keys to their rank ----------------
__global__ __launch_bounds__(256) void scatter_kernel(const u64* __restrict__ comp,
        const u32* __restrict__ meta, const u32* __restrict__ rankArr,
        u64* __restrict__ sorted) {
    u32 cnt = meta[0];
    int n = (int)(cnt < (u32)CAP ? cnt : (u32)CAP);
    int i = blockIdx.x * 256 + threadIdx.x;
    if (i < n) {
        u32 r = rankArr[i];
        if (r < (u32)K_TOP) sorted[r] = comp[i];     // keys unique -> permutation
    }
}

// ---------------- kernel 5: wave-per-anchor gather of boxes/classes/scores ---------
__global__ __launch_bounds__(256) void gather_kernel(const u64* __restrict__ sorted,
        const float* __restrict__ preds, float* __restrict__ boxes,
        float* __restrict__ scores, float* __restrict__ classes) {
#pragma clang fp contract(off)
    int lane = threadIdx.x & 63;
    int i = blockIdx.x * 4 + (threadIdx.x >> 6);     // i in [0, 8192)
    u64 key = sorted[i];
    u32 sb = (u32)(key >> 32);
    float score = __uint_as_float(sb);
    if (score > 0.0f) {                               // uniform across the wave
        u32 idx = ~(u32)(key & 0xffffffffull);
        const float* p = preds + (size_t)idx * ROWLEN;
        float v0 = p[lane];
        float v1 = (lane < ROWLEN - 64) ? p[64 + lane] : 0.0f;
        float obj = __shfl(v0, 4);
        u64 kb = 0;
        if (lane >= 5) {
            float q = v0 * obj;                       // class lane-5
            kb = ((u64)__float_as_uint(q) << 8) | (u32)(255 - (lane - 5));
        }
        if (lane < 21) {
            float q = v1 * obj;                       // class 59+lane
            u64 kb2 = ((u64)__float_as_uint(q) << 8) | (u32)(255 - (59 + lane));
            if (kb2 > kb) kb = kb2;
        }
        for (int off = 32; off; off >>= 1) {
            u64 o = __shfl_xor(kb, off);
            if (o > kb) kb = o;
        }
        u32 cls = 255u - (u32)(kb & 0xffull);
        float x = __shfl(v0, 0), y = __shfl(v0, 1);
        float w = __shfl(v0, 2), h = __shfl(v0, 3);
        if (lane == 0) {
            boxes[i * 4 + 0] = y - h * 0.5f;          // ymin
            boxes[i * 4 + 1] = x - w * 0.5f;          // xmin
            boxes[i * 4 + 2] = y + h * 0.5f;          // ymax
            boxes[i * 4 + 3] = x + w * 0.5f;          // xmax
            scores[i] = score;
            classes[i] = (float)cls;
        }
    } else if (lane == 0) {
        boxes[i * 4 + 0] = 0.0f; boxes[i * 4 + 1] = 0.0f;
        boxes[i * 4 + 2] = 0.0f; boxes[i * 4 + 3] = 0.0f;
        scores[i] = 0.0f;
        classes[i] = 0.0f;
    }
}

// ---------------- kernel 6: full suppression bitmask, broadcast + transpose --------
// Round-13 post-mortem: VALU 54% -- cost dominated by (a) IEEE fp32 div per IoU,
// (b) per-thread area_j recompute, (c) 16-distinct-address LDS reads. This version:
// block = 64 rows x 16 words, thread owns words w+4q -> all lanes of a wave share
// the word => every sbox/sarea read is an LDS BROADCAST. area_j precomputed once.
// Division replaced by a two-sided multiply filter (margins 0.449/0.451 >> ulp, so
// decisions are bit-identical to fl(inter/d) > 0.45f; d >= 1e-9 > 0 by fp
// monotonicity since inter <= min(ai,aj)); exact IEEE div only in the ~0.4% band.
// Output via LDS transpose: 32B/thread, 16 words/row = full 128B lines (no RMW).
// Grid (8,128): all 1024 blocks co-resident (4/CU), zero tail.
__global__ __launch_bounds__(256) void mask_kernel(const float* __restrict__ boxes,
        u64* __restrict__ mask) {
#pragma clang fp contract(off)
    __shared__ float4 sbox[1024];
    __shared__ float sarea[1024];
    __shared__ u64 wtile[64 * 17];                    // [row][word], stride 17 pad
    int ct = blockIdx.x;                              // col tile 0..7  (1024 cols)
    int rb = blockIdx.y;                              // row tile 0..127 (64 rows)
    int t = threadIdx.x;
    for (int jj = t; jj < 1024; jj += 256) {
        float4 b = ((const float4*)boxes)[ct * 1024 + jj];
        sbox[jj] = b;
        sarea[jj] = (b.z - b.x) * (b.w - b.y);
    }
    __syncthreads();
    int lane = t & 63, w = t >> 6;                    // wave id = word group
    int r = rb * 64 + lane;                           // this thread's row
    float4 bi = ((const float4*)boxes)[r];
    float ai = (bi.z - bi.x) * (bi.w - bi.y);
    int rbb = rb * 64;
#pragma unroll
    for (int q = 0; q < 4; ++q) {
        int wq = w + q * 4;                           // wave-uniform word
        int j0g = ct * 1024 + wq * 64;
        u64 bits = 0;
        if (j0g + 63 > rbb) {                         // word not entirely <= rows
            for (int k = 0; k < 64; ++k) {
                int j = j0g + k;
                float4 bj = sbox[wq * 64 + k];        // broadcast
                float aj = sarea[wq * 64 + k];        // broadcast
                float ty = fmaxf(bi.x, bj.x);
                float tx = fmaxf(bi.y, bj.y);
                float by = fminf(bi.z, bj.z);
                float bx = fminf(bi.w, bj.w);
                float ih = fmaxf(by - ty, 0.0f);
                float iw = fmaxf(bx - tx, 0.0f);
                float inter = ih * iw;
                float uni = (ai + aj) - inter;
                float d = uni + 1e-9f;
                bool kp;
                if (inter > 0.451f * d) kp = true;
                else if (inter <= 0.449f * d) kp = false;
                else kp = (inter / d > IOU_THRES);    // rare exact path
                if (kp && j > r) bits |= (1ull << k);
            }
        }
        wtile[lane * 17 + wq] = bits;
    }
    __syncthreads();
    // transposed write: thread t -> row rr, words wbase..wbase+3 (32B contiguous);
    // 4 consecutive threads cover one full 128B line.
    int rr = t >> 2, wbase = (t & 3) * 4;
    u64 b0 = wtile[rr * 17 + wbase + 0];
    u64 b1 = wtile[rr * 17 + wbase + 1];
    u64 b2 = wtile[rr * 17 + wbase + 2];
    u64 b3 = wtile[rr * 17 + wbase + 3];
    u64* dst = &mask[(size_t)(rb * 64 + rr) * 128 + ct * 16 + wbase];
    *(uint4*)dst = make_uint4((u32)b0, (u32)(b0 >> 32), (u32)b1, (u32)(b1 >> 32));
    *(uint4*)(dst + 2) = make_uint4((u32)b2, (u32)(b2 >> 32), (u32)b3, (u32)(b3 >> 32));
}

// ---------------- kernel 6b: validity words (rem init) for the scan ----------------
__global__ __launch_bounds__(256) void valid_kernel(const float* __restrict__ scores,
        u64* __restrict__ remw) {
    int w = blockIdx.x * 4 + (threadIdx.x >> 6);      // 128 waves over 32 blocks
    int lane = threadIdx.x & 63;
    u64 b = __ballot(scores[w * 64 + lane] > 0.0f);
    if (lane == 0) remw[w] = b;
}

// ---------------- kernel 7: single-wave greedy scan, 16 LDS windows, no fallback ---
__device__ __forceinline__ u64 rfl64(u64 v) {
    u32 lo = (u32)__builtin_amdgcn_readfirstlane((int)(u32)v);
    u32 hi = (u32)__builtin_amdgcn_readfirstlane((int)(u32)(v >> 32));
    return ((u64)hi << 32) | lo;
}

__device__ __forceinline__ u64 bcast64(u64 v, int srclane) {
    u32 lo = (u32)__builtin_amdgcn_readlane((int)(u32)v, srclane);
    u32 hi = (u32)__builtin_amdgcn_readlane((int)(u32)(v >> 32), srclane);
    return ((u64)hi << 32) | lo;
}

__device__ __forceinline__ u64 shfl_xor64(u64 v, int m) {
    u32 lo = __shfl_xor((u32)v, m, 64);
    u32 hi = __shfl_xor((u32)(v >> 32), m, 64);
    return ((u64)hi << 32) | lo;
}

__global__ __launch_bounds__(64) void nms_scan_kernel(const u64* __restrict__ mask,
        const u64* __restrict__ remw, const float* __restrict__ boxes,
        const float* __restrict__ scores, const float* __restrict__ classes,
        float* __restrict__ out) {
    __shared__ u64 sub[WIN * SSTR];                   // 36 KB padded window submatrix
    __shared__ u32 ki[MAX_DET + 8];                   // kept indices (ascending)
    int lane = threadIdx.x;                           // exactly one wave
    int n = 0;
    for (int win = 0; win < NWIN && n < MAX_DET; ++win) {
        int rbase = win * WIN;
        __syncthreads();                              // prev window's sub reads done
        // stage diag window: rows [rbase, rbase+WIN) x words [win*8, win*8+8)
#pragma unroll 8
        for (int it = 0; it < 32; ++it) {
            int idx = it * 64 + lane;                 // uint4 index, 2048 total
            int r = idx >> 2, j = (idx & 3) * 2;
            uint4 v = *(const uint4*)&mask[(size_t)(rbase + r) * 128 + win * 8 + j];
            sub[r * SSTR + j]     = ((u64)v.y << 32) | v.x;
            sub[r * SSTR + j + 1] = ((u64)v.w << 32) | v.z;
        }
        // fold suppression from keeps in earlier windows (parallel over keeps)
        u64 acc[8] = {0, 0, 0, 0, 0, 0, 0, 0};
        for (int m = lane; m < n; m += 64) {
            int k = (int)ki[m];
            const u64* rp = &mask[(size_t)k * 128 + win * 8];
#pragma unroll
            for (int j = 0; j < 8; ++j) acc[j] |= rp[j];
        }
#pragma unroll
        for (int j = 0; j < 8; ++j)
            for (int off = 32; off; off >>= 1) acc[j] |= shfl_xor64(acc[j], off);
        __syncthreads();
        u64 diag[8];
#pragma unroll
        for (int sw = 0; sw < 8; ++sw) diag[sw] = sub[(sw * 64 + lane) * SSTR + sw];
        int n0 = n;
        u64 keptW[8] = {0, 0, 0, 0, 0, 0, 0, 0};
#pragma unroll
        for (int sw = 0; sw < 8; ++sw) {
            if (n < MAX_DET) {
                // suppression from keeps in earlier subwords of THIS window
                u64 acc2 = 0;
#pragma unroll
                for (int wp = 0; wp < 8; ++wp) {
                    if (wp < sw) {
                        if ((keptW[wp] >> lane) & 1ull)
                            acc2 |= sub[(wp * 64 + lane) * SSTR + sw];
                    }
                }
                for (int off = 32; off; off >>= 1) acc2 |= shfl_xor64(acc2, off);
                u64 cur = rfl64(remw[win * 8 + sw]) & ~rfl64(acc[sw]) & ~rfl64(acc2);
                u64 kw = 0;
                while (cur != 0ull && n < MAX_DET) {  // uniform scalar pop chain
                    int b = __ffsll((unsigned long long)cur) - 1;
                    u64 slice = bcast64(diag[sw], b); // row (sw*64+b), word sw
                    kw |= (1ull << b);
                    cur &= ~(slice | (1ull << b));
                    ++n;
                }
                keptW[sw] = kw;
            }
        }
        // append kept indices (parallel; ascending index = greedy order)
        int base = n0;
#pragma unroll
        for (int sw = 0; sw < 8; ++sw) {
            u64 kw = keptW[sw];
            if ((kw >> lane) & 1ull) {
                int rr = (int)__popcll(kw & ((1ull << lane) - 1ull));
                ki[base + rr] = (u32)(rbase + sw * 64 + lane);
            }
            base += (int)__popcll(kw);
        }
        __syncthreads();
    }
    __syncthreads();
    // ---- parallel output phase: lane m handles detection m (5 strided rounds) ----
    for (int m = lane; m < MAX_DET; m += 64) {
        float4 b = make_float4(0.0f, 0.0f, 0.0f, 0.0f);
        float c = 0.0f, s = 0.0f;
        if (m < n) {
            int k = (int)ki[m];
            b = ((const float4*)boxes)[k];
            c = classes[k];
            s = scores[k];
        }
        ((float4*)out)[m] = b;
        out[1200 + m] = c;
        out[1500 + m] = s;
    }
}

// ---------------- launch ----------------
extern "C" void kernel_launch(void* const* d_in, const int* in_sizes, int n_in,
                              void* d_out, int out_size, void* d_ws, size_t ws_size,
                              hipStream_t stream) {
    const float* preds = (const float*)d_in[0];
    char* ws = (char*)d_ws;

    // ws layout (bytes), total 9991104:
    //   [0, 262144)            sumhist     u32[65536]
    //   [262144, 262208)       meta        u32[16]   ([0]=counter, [1]=thresh)
    //   [262208, 263232)       remw        u64[128]
    //   [263232, 328768)       sorted      u64[8192]
    //   [328768, 1144768)      keys        u64[102000] (dead after compact;
    //                                      front 130560 B reused as rankArr)
    //   [1144768, 1405888)     comp        u64[32640]
    //   [1405888, 1536960)     top_boxes   f32[8192*4]
    //   [1536960, 1569728)     top_scores  f32[8192]
    //   [1569728, 1602496)     top_classes f32[8192]
    //   [1602496, 9991104)     mask        u64[8192*128]  (8 MB; doubles as the
    //                                      32-plane histogram before mask_kernel)
    u32*   sumhist = (u32*)(ws + 0);
    u32*   meta    = (u32*)(ws + 262144);
    u64*   remw    = (u64*)(ws + 262208);
    u64*   sorted  = (u64*)(ws + 263232);
    u64*   keys    = (u64*)(ws + 328768);
    u32*   rankArr = (u32*)(ws + 328768);            // aliases keys (dead by then)
    u64*   comp    = (u64*)(ws + 1144768);
    float* tboxes  = (float*)(ws + 1405888);
    float* tscores = (float*)(ws + 1536960);
    float* tclass  = (float*)(ws + 1569728);
    u64*   mask    = (u64*)(ws + 1602496);
    u32*   histP   = (u32*)(ws + 1602496);           // aliases mask region (earlier)
    float* out     = (float*)d_out;

    hipMemsetAsync(ws, 0, 328768, stream);           // sumhist+meta+remw+sorted
    hipMemsetAsync(histP, 0, (size_t)NPLANE * 65536 * 4, stream);  // hist planes (8 MB)

    score_key_kernel<<<(NA + 3) / 4, 256, 0, stream>>>(preds, keys, histP);
    reduce_hist_kernel<<<256, 256, 0, stream>>>(histP, sumhist);
    cutoff_kernel<<<1, 1024, 0, stream>>>(sumhist, meta);
    compact_kernel<<<(NA + 255) / 256, 256, 0, stream>>>(keys, meta, comp);
    hipMemsetAsync(rankArr, 0, (size_t)CAP * 4, stream);   // keys dead: zero rankArr
    rank_partial_kernel<<<dim3((CAP + 255) / 256, (CAP + 1023) / 1024), 256, 0, stream>>>(
            comp, meta, rankArr);
    scatter_kernel<<<(CAP + 255) / 256, 256, 0, stream>>>(comp, meta, rankArr, sorted);
    gather_kernel<<<K_TOP / 4, 256, 0, stream>>>(sorted, preds, tboxes, tscores, tclass);
    mask_kernel<<<dim3(8, 128), 256, 0, stream>>>(tboxes, mask);
    valid_kernel<<<32, 256, 0, stream>>>(tscores, remw);
    nms_scan_kernel<<<1, 64, 0, stream>>>(mask, remw, tboxes, tscores, tclass, out);
}

// Round 15
// 216.684 us; speedup vs baseline: 1.0633x; 1.0633x over previous
//
#include <hip/hip_runtime.h>
#include <cstdint>

#define CONF_THRES 0.25f
#define IOU_THRES  0.45f
#define MAX_DET    300
#define K_TOP      8192
#define NA         102000
#define NCLS       80
#define ROWLEN     85
#define CAP        32640
#define NPLANE     32
#define WIN        512
#define NWIN       (K_TOP / WIN)
#define SSTR       9            // LDS row stride in u64 (pad 8->9: bank spread)

typedef unsigned long long u64;
typedef unsigned int u32;

// ---------------- kernel 1: wave-per-anchor scores -> sortable keys + histogram ----
__global__ __launch_bounds__(256) void score_key_kernel(const float* __restrict__ preds,
        u64* __restrict__ keys, u32* __restrict__ histP) {
#pragma clang fp contract(off)
    int lane = threadIdx.x & 63;
    int i = blockIdx.x * 4 + (threadIdx.x >> 6);     // 4 waves/block, 1 anchor/wave
    if (i >= NA) return;
    const float* p = preds + (size_t)i * ROWLEN;
    float v0 = p[lane];                               // offsets 0..63
    float v1 = (lane < ROWLEN - 64) ? p[64 + lane] : 0.0f; // offsets 64..84
    float obj = __shfl(v0, 4);
    float m = (lane >= 5) ? v0 : 0.0f;                // classes 0..58 (scores >= 0)
    m = fmaxf(m, (lane < 21) ? v1 : 0.0f);            // classes 59..79
    for (int off = 32; off; off >>= 1) m = fmaxf(m, __shfl_xor(m, off));
    if (lane == 0) {
        float score = (obj > CONF_THRES) ? m * obj : 0.0f;
        u32 sb = __float_as_uint(score);              // score >= 0: order-preserving bits
        keys[i] = ((u64)sb << 32) | (u32)(~(u32)i);   // tie-break: smaller index wins
        if (sb != 0u)
            atomicAdd(&histP[((u32)blockIdx.x & (NPLANE - 1u)) * 65536u + (sb >> 16)], 1u);
    }
}

// ---------------- kernel 1b: fold 32 histogram planes -> sumhist ----------------
__global__ __launch_bounds__(256) void reduce_hist_kernel(const u32* __restrict__ histP,
        u32* __restrict__ sumhist) {
    int bin = blockIdx.x * 256 + threadIdx.x;         // grid 256 -> 65536 bins
    u32 s = 0;
#pragma unroll
    for (int r = 0; r < NPLANE; ++r) s += histP[r * 65536 + bin];
    sumhist[bin] = s;
}

// ---------------- kernel 2: find threshold bucket for top-K (parallel scan) --------
__global__ __launch_bounds__(1024) void cutoff_kernel(const u32* __restrict__ hist,
        u32* __restrict__ meta) {
    __shared__ u32 suf[1024];
    __shared__ int cbs;
    __shared__ u32 above_s;
    int t = threadIdx.x;
    u32 s = 0;
    const u32* hb = hist + t * 64;
    for (int b = 0; b < 64; ++b) s += hb[b];
    suf[t] = s;
    if (t == 0) { cbs = -1; above_s = 0; }
    __syncthreads();
    for (int off = 1; off < 1024; off <<= 1) {
        u32 add = (t + off < 1024) ? suf[t + off] : 0u;
        __syncthreads();
        suf[t] += add;
        __syncthreads();
    }
    u32 st = suf[t];
    u32 stn = (t < 1023) ? suf[t + 1] : 0u;
    if (st >= (u32)K_TOP && stn < (u32)K_TOP) {       // at most one thread
        cbs = t;
        above_s = stn;                                 // sum of chunks above cb
    }
    __syncthreads();
    int cb = cbs;
    if (t < 64) {                                      // wave 0 does the fine pass
        u32 thresh = 0;
        if (cb >= 0) {
            u32 above = above_s;
            u32 v = hist[cb * 64 + t];
            for (int off = 1; off < 64; off <<= 1) {
                u32 o = __shfl_down(v, off);
                if (t + off < 64) v += o;
            }
            u64 bal = __ballot(v + above >= (u32)K_TOP);
            int bstar = 63 - __builtin_clzll((unsigned long long)bal);
            thresh = ((u32)(cb * 64 + bstar)) << 16;
        }
        if (t == 0) meta[1] = thresh;                  // meta[0] zeroed by memset
    }
}

// ---------------- kernel 3: compact candidates above threshold ----------------
__global__ __launch_bounds__(256) void compact_kernel(const u64* __restrict__ keys,
        u32* __restrict__ meta, u64* __restrict__ comp) {
    __shared__ u32 woff[4];
    __shared__ u32 bbase;
    int i = blockIdx.x * 256 + threadIdx.x;
    int wid = threadIdx.x >> 6, lane = threadIdx.x & 63;
    u64 key = (i < NA) ? keys[i] : 0ull;
    u32 sb = (u32)(key >> 32);
    u32 th = meta[1];
    bool take = (i < NA) && (sb != 0u) && (sb >= th);
    u64 bal = __ballot(take);
    if (lane == 0) woff[wid] = (u32)__popcll(bal);
    __syncthreads();
    if (threadIdx.x == 0) {
        u32 t0 = woff[0], t1 = woff[1], t2 = woff[2], t3 = woff[3];
        bbase = atomicAdd(&meta[0], t0 + t1 + t2 + t3);
        woff[0] = 0; woff[1] = t0; woff[2] = t0 + t1; woff[3] = t0 + t1 + t2;
    }
    __syncthreads();
    if (take) {
        u32 pos = bbase + woff[wid] + (u32)__popcll(bal & ((1ull << lane) - 1ull));
        if (pos < CAP) comp[pos] = key;
    }
}

// ---------------- kernel 4a: 2-D partial rank-by-counting ----------------
__global__ __launch_bounds__(256) void rank_partial_kernel(const u64* __restrict__ comp,
        const u32* __restrict__ meta, u32* __restrict__ rankArr) {
    __shared__ u64 tile[1024];
    u32 cnt = meta[0];
    int n = (int)(cnt < (u32)CAP ? cnt : (u32)CAP);
    int i0 = blockIdx.x * 256;
    int j0 = blockIdx.y * 1024;
    if (i0 >= n || j0 >= n) return;                  // uniform early exit
    int lim = n - j0; if (lim > 1024) lim = 1024;
    for (int k = threadIdx.x; k < 1024; k += 256)
        tile[k] = (k < lim) ? comp[j0 + k] : 0ull;
    __syncthreads();
    int i = i0 + threadIdx.x;
    if (i < n) {
        u64 key = comp[i];
        u32 r = 0;
#pragma unroll 8
        for (int j = 0; j < 1024; ++j) r += (tile[j] > key) ? 1u : 0u;
        atomicAdd(&rankArr[i], r);
    }
}

// ---------------- kernel 4b: scatter keys to their rank ----------------
__global__ __launch_bounds__(256) void scatter_kernel(const u64* __restrict__ comp,
        const u32* __restrict__ meta, const u32* __restrict__ rankArr,
        u64* __restrict__ sorted) {
    u32 cnt = meta[0];
    int n = (int)(cnt < (u32)CAP ? cnt : (u32)CAP);
    int i = blockIdx.x * 256 + threadIdx.x;
    if (i < n) {
        u32 r = rankArr[i];
        if (r < (u32)K_TOP) sorted[r] = comp[i];     // keys unique -> permutation
    }
}

// ---------------- kernel 5: wave-per-anchor gather of boxes/classes/scores ---------
__global__ __launch_bounds__(256) void gather_kernel(const u64* __restrict__ sorted,
        const float* __restrict__ preds, float* __restrict__ boxes,
        float* __restrict__ scores, float* __restrict__ classes) {
#pragma clang fp contract(off)
    int lane = threadIdx.x & 63;
    int i = blockIdx.x * 4 + (threadIdx.x >> 6);     // i in [0, 8192)
    u64 key = sorted[i];
    u32 sb = (u32)(key >> 32);
    float score = __uint_as_float(sb);
    if (score > 0.0f) {                               // uniform across the wave
        u32 idx = ~(u32)(key & 0xffffffffull);
        const float* p = preds + (size_t)idx * ROWLEN;
        float v0 = p[lane];
        float v1 = (lane < ROWLEN - 64) ? p[64 + lane] : 0.0f;
        float obj = __shfl(v0, 4);
        u64 kb = 0;
        if (lane >= 5) {
            float q = v0 * obj;                       // class lane-5
            kb = ((u64)__float_as_uint(q) << 8) | (u32)(255 - (lane - 5));
        }
        if (lane < 21) {
            float q = v1 * obj;                       // class 59+lane
            u64 kb2 = ((u64)__float_as_uint(q) << 8) | (u32)(255 - (59 + lane));
            if (kb2 > kb) kb = kb2;
        }
        for (int off = 32; off; off >>= 1) {
            u64 o = __shfl_xor(kb, off);
            if (o > kb) kb = o;
        }
        u32 cls = 255u - (u32)(kb & 0xffull);
        float x = __shfl(v0, 0), y = __shfl(v0, 1);
        float w = __shfl(v0, 2), h = __shfl(v0, 3);
        if (lane == 0) {
            boxes[i * 4 + 0] = y - h * 0.5f;          // ymin
            boxes[i * 4 + 1] = x - w * 0.5f;          // xmin
            boxes[i * 4 + 2] = y + h * 0.5f;          // ymax
            boxes[i * 4 + 3] = x + w * 0.5f;          // xmax
            scores[i] = score;
            classes[i] = (float)cls;
        }
    } else if (lane == 0) {
        boxes[i * 4 + 0] = 0.0f; boxes[i * 4 + 1] = 0.0f;
        boxes[i * 4 + 2] = 0.0f; boxes[i * 4 + 3] = 0.0f;
        scores[i] = 0.0f;
        classes[i] = 0.0f;
    }
}

// ---------------- kernel 6: full suppression bitmask, branch-free exact IoU --------
// Round-14 post-mortem: the "rare" exact-divide path fired in ~23% of wave-iters
// (64 lanes x 0.4% band) and added branch overhead everywhere; VALU 31%, VGPR 44.
// Replacement: fl(inter/d) > 0.45f  <=>  inter/d > B,  B = 0.45f + 2^-26 (half-ulp;
// 0.45f mantissa even so the tie rounds DOWN -> strict). B is (2m+1)*2^-26 (25-bit
// odd), d is 24-bit => B*d exact in double; (double)inter > B*(double)d is a
// bit-identical, division-free, branch-free decision. d > 0 guaranteed (fp
// monotonicity: inter <= min(ai,aj) <= fl(ai+aj)). j>r test hoisted into a
// per-word u64 jmask. Broadcast LDS layout + transpose write kept from round 14.
__global__ __launch_bounds__(256) void mask_kernel(const float* __restrict__ boxes,
        u64* __restrict__ mask) {
#pragma clang fp contract(off)
    __shared__ float4 sbox[1024];
    __shared__ float sarea[1024];
    __shared__ u64 wtile[64 * 17];                    // [row][word], stride 17 pad
    int ct = blockIdx.x;                              // col tile 0..7  (1024 cols)
    int rb = blockIdx.y;                              // row tile 0..127 (64 rows)
    int t = threadIdx.x;
    for (int jj = t; jj < 1024; jj += 256) {
        float4 b = ((const float4*)boxes)[ct * 1024 + jj];
        sbox[jj] = b;
        sarea[jj] = (b.z - b.x) * (b.w - b.y);
    }
    __syncthreads();
    int lane = t & 63, w = t >> 6;                    // wave id = word group
    int r = rb * 64 + lane;                           // this thread's row
    float4 bi = ((const float4*)boxes)[r];
    float ai = (bi.z - bi.x) * (bi.w - bi.y);
    const double B = (double)IOU_THRES + 0x1p-26;     // 0.45f + half-ulp, exact
#pragma unroll
    for (int q = 0; q < 4; ++q) {
        int wq = w + q * 4;                           // wave-uniform word
        int j0g = ct * 1024 + wq * 64;
        // jmask: bit k set iff j0g+k > r
        u64 jmask;
        if (r < j0g) jmask = ~0ull;
        else if (r >= j0g + 63) jmask = 0ull;
        else jmask = (~0ull) << (r - j0g + 1);
        u64 bits = 0;
        if (jmask != 0ull) {                          // skip fully-lower words
#pragma unroll 4
            for (int k = 0; k < 64; ++k) {
                float4 bj = sbox[wq * 64 + k];        // broadcast
                float aj = sarea[wq * 64 + k];        // broadcast
                float ty = fmaxf(bi.x, bj.x);
                float tx = fmaxf(bi.y, bj.y);
                float by = fminf(bi.z, bj.z);
                float bx = fminf(bi.w, bj.w);
                float ih = fmaxf(by - ty, 0.0f);
                float iw = fmaxf(bx - tx, 0.0f);
                float inter = ih * iw;
                float d = ((ai + aj) - inter) + 1e-9f;
                if ((double)inter > B * (double)d) bits |= (1ull << k);
            }
            bits &= jmask;
        }
        wtile[lane * 17 + wq] = bits;
    }
    __syncthreads();
    // transposed write: thread t -> row rr, words wbase..wbase+3 (32B contiguous);
    // 4 consecutive threads cover one full 128B line.
    int rr = t >> 2, wbase = (t & 3) * 4;
    u64 b0 = wtile[rr * 17 + wbase + 0];
    u64 b1 = wtile[rr * 17 + wbase + 1];
    u64 b2 = wtile[rr * 17 + wbase + 2];
    u64 b3 = wtile[rr * 17 + wbase + 3];
    u64* dst = &mask[(size_t)(rb * 64 + rr) * 128 + ct * 16 + wbase];
    *(uint4*)dst = make_uint4((u32)b0, (u32)(b0 >> 32), (u32)b1, (u32)(b1 >> 32));
    *(uint4*)(dst + 2) = make_uint4((u32)b2, (u32)(b2 >> 32), (u32)b3, (u32)(b3 >> 32));
}

// ---------------- kernel 6b: validity words (rem init) for the scan ----------------
__global__ __launch_bounds__(256) void valid_kernel(const float* __restrict__ scores,
        u64* __restrict__ remw) {
    int w = blockIdx.x * 4 + (threadIdx.x >> 6);      // 128 waves over 32 blocks
    int lane = threadIdx.x & 63;
    u64 b = __ballot(scores[w * 64 + lane] > 0.0f);
    if (lane == 0) remw[w] = b;
}

// ---------------- kernel 7: single-wave greedy scan, 16 LDS windows, no fallback ---
__device__ __forceinline__ u64 rfl64(u64 v) {
    u32 lo = (u32)__builtin_amdgcn_readfirstlane((int)(u32)v);
    u32 hi = (u32)__builtin_amdgcn_readfirstlane((int)(u32)(v >> 32));
    return ((u64)hi << 32) | lo;
}

__device__ __forceinline__ u64 bcast64(u64 v, int srclane) {
    u32 lo = (u32)__builtin_amdgcn_readlane((int)(u32)v, srclane);
    u32 hi = (u32)__builtin_amdgcn_readlane((int)(u32)(v >> 32), srclane);
    return ((u64)hi << 32) | lo;
}

__device__ __forceinline__ u64 shfl_xor64(u64 v, int m) {
    u32 lo = __shfl_xor((u32)v, m, 64);
    u32 hi = __shfl_xor((u32)(v >> 32), m, 64);
    return ((u64)hi << 32) | lo;
}

__global__ __launch_bounds__(64) void nms_scan_kernel(const u64* __restrict__ mask,
        const u64* __restrict__ remw, const float* __restrict__ boxes,
        const float* __restrict__ scores, const float* __restrict__ classes,
        float* __restrict__ out) {
    __shared__ u64 sub[WIN * SSTR];                   // 36 KB padded window submatrix
    __shared__ u32 ki[MAX_DET + 8];                   // kept indices (ascending)
    int lane = threadIdx.x;                           // exactly one wave
    int n = 0;
    for (int win = 0; win < NWIN && n < MAX_DET; ++win) {
        int rbase = win * WIN;
        __syncthreads();                              // prev window's sub reads done
        // stage diag window: rows [rbase, rbase+WIN) x words [win*8, win*8+8)
#pragma unroll 8
        for (int it = 0; it < 32; ++it) {
            int idx = it * 64 + lane;                 // uint4 index, 2048 total
            int r = idx >> 2, j = (idx & 3) * 2;
            uint4 v = *(const uint4*)&mask[(size_t)(rbase + r) * 128 + win * 8 + j];
            sub[r * SSTR + j]     = ((u64)v.y << 32) | v.x;
            sub[r * SSTR + j + 1] = ((u64)v.w << 32) | v.z;
        }
        // fold suppression from keeps in earlier windows (parallel over keeps)
        u64 acc[8] = {0, 0, 0, 0, 0, 0, 0, 0};
        for (int m = lane; m < n; m += 64) {
            int k = (int)ki[m];
            const u64* rp = &mask[(size_t)k * 128 + win * 8];
#pragma unroll
            for (int j = 0; j < 8; ++j) acc[j] |= rp[j];
        }
#pragma unroll
        for (int j = 0; j < 8; ++j)
            for (int off = 32; off; off >>= 1) acc[j] |= shfl_xor64(acc[j], off);
        __syncthreads();
        u64 diag[8];
#pragma unroll
        for (int sw = 0; sw < 8; ++sw) diag[sw] = sub[(sw * 64 + lane) * SSTR + sw];
        int n0 = n;
        u64 keptW[8] = {0, 0, 0, 0, 0, 0, 0, 0};
#pragma unroll
        for (int sw = 0; sw < 8; ++sw) {
            if (n < MAX_DET) {
                // suppression from keeps in earlier subwords of THIS window
                u64 acc2 = 0;
#pragma unroll
                for (int wp = 0; wp < 8; ++wp) {
                    if (wp < sw) {
                        if ((keptW[wp] >> lane) & 1ull)
                            acc2 |= sub[(wp * 64 + lane) * SSTR + sw];
                    }
                }
                for (int off = 32; off; off >>= 1) acc2 |= shfl_xor64(acc2, off);
                u64 cur = rfl64(remw[win * 8 + sw]) & ~rfl64(acc[sw]) & ~rfl64(acc2);
                u64 kw = 0;
                while (cur != 0ull && n < MAX_DET) {  // uniform scalar pop chain
                    int b = __ffsll((unsigned long long)cur) - 1;
                    u64 slice = bcast64(diag[sw], b); // row (sw*64+b), word sw
                    kw |= (1ull << b);
                    cur &= ~(slice | (1ull << b));
                    ++n;
                }
                keptW[sw] = kw;
            }
        }
        // append kept indices (parallel; ascending index = greedy order)
        int base = n0;
#pragma unroll
        for (int sw = 0; sw < 8; ++sw) {
            u64 kw = keptW[sw];
            if ((kw >> lane) & 1ull) {
                int rr = (int)__popcll(kw & ((1ull << lane) - 1ull));
                ki[base + rr] = (u32)(rbase + sw * 64 + lane);
            }
            base += (int)__popcll(kw);
        }
        __syncthreads();
    }
    __syncthreads();
    // ---- parallel output phase: lane m handles detection m (5 strided rounds) ----
    for (int m = lane; m < MAX_DET; m += 64) {
        float4 b = make_float4(0.0f, 0.0f, 0.0f, 0.0f);
        float c = 0.0f, s = 0.0f;
        if (m < n) {
            int k = (int)ki[m];
            b = ((const float4*)boxes)[k];
            c = classes[k];
            s = scores[k];
        }
        ((float4*)out)[m] = b;
        out[1200 + m] = c;
        out[1500 + m] = s;
    }
}

// ---------------- launch ----------------
extern "C" void kernel_launch(void* const* d_in, const int* in_sizes, int n_in,
                              void* d_out, int out_size, void* d_ws, size_t ws_size,
                              hipStream_t stream) {
    const float* preds = (const float*)d_in[0];
    char* ws = (char*)d_ws;

    // ws layout (bytes), total 9991104:
    //   [0, 262144)            sumhist     u32[65536]
    //   [262144, 262208)       meta        u32[16]   ([0]=counter, [1]=thresh)
    //   [262208, 263232)       remw        u64[128]
    //   [263232, 328768)       sorted      u64[8192]
    //   [328768, 1144768)      keys        u64[102000] (dead after compact;
    //                                      front 130560 B reused as rankArr)
    //   [1144768, 1405888)     comp        u64[32640]
    //   [1405888, 1536960)     top_boxes   f32[8192*4]
    //   [1536960, 1569728)     top_scores  f32[8192]
    //   [1569728, 1602496)     top_classes f32[8192]
    //   [1602496, 9991104)     mask        u64[8192*128]  (8 MB; doubles as the
    //                                      32-plane histogram before mask_kernel)
    u32*   sumhist = (u32*)(ws + 0);
    u32*   meta    = (u32*)(ws + 262144);
    u64*   remw    = (u64*)(ws + 262208);
    u64*   sorted  = (u64*)(ws + 263232);
    u64*   keys    = (u64*)(ws + 328768);
    u32*   rankArr = (u32*)(ws + 328768);            // aliases keys (dead by then)
    u64*   comp    = (u64*)(ws + 1144768);
    float* tboxes  = (float*)(ws + 1405888);
    float* tscores = (float*)(ws + 1536960);
    float* tclass  = (float*)(ws + 1569728);
    u64*   mask    = (u64*)(ws + 1602496);
    u32*   histP   = (u32*)(ws + 1602496);           // aliases mask region (earlier)
    float* out     = (float*)d_out;

    hipMemsetAsync(ws, 0, 328768, stream);           // sumhist+meta+remw+sorted
    hipMemsetAsync(histP, 0, (size_t)NPLANE * 65536 * 4, stream);  // hist planes (8 MB)

    score_key_kernel<<<(NA + 3) / 4, 256, 0, stream>>>(preds, keys, histP);
    reduce_hist_kernel<<<256, 256, 0, stream>>>(histP, sumhist);
    cutoff_kernel<<<1, 1024, 0, stream>>>(sumhist, meta);
    compact_kernel<<<(NA + 255) / 256, 256, 0, stream>>>(keys, meta, comp);
    hipMemsetAsync(rankArr, 0, (size_t)CAP * 4, stream);   // keys dead: zero rankArr
    rank_partial_kernel<<<dim3((CAP + 255) / 256, (CAP + 1023) / 1024), 256, 0, stream>>>(
            comp, meta, rankArr);
    scatter_kernel<<<(CAP + 255) / 256, 256, 0, stream>>>(comp, meta, rankArr, sorted);
    gather_kernel<<<K_TOP / 4, 256, 0, stream>>>(sorted, preds, tboxes, tscores, tclass);
    mask_kernel<<<dim3(8, 128), 256, 0, stream>>>(tboxes, mask);
    valid_kernel<<<32, 256, 0, stream>>>(tscores, remw);
    nms_scan_kernel<<<1, 64, 0, stream>>>(mask, remw, tboxes, tscores, tclass, out);
}